// Round 8
// baseline (364.651 us; speedup 1.0000x reference)
//
#include <hip/hip_runtime.h>
#include <math.h>

#define NN 128
#define CC 64
#define TT 288
#define VV 16
#define SS 3
#define ICC 16

#define SLICES 12
#define TSL (TT / SLICES)      // 24 t's per slice
#define CHUNKS (TSL / 8)       // 3 chunks of 8 t's

#define OTB 16                 // k_out t's per block (two 8-t sub-tiles)

typedef __attribute__((ext_vector_type(8))) short s16x8;
typedef __attribute__((ext_vector_type(4))) float f32x4;

#define MFMA16(a, b, c) __builtin_amdgcn_mfma_f32_16x16x32_bf16(a, b, c, 0, 0, 0)

__device__ __forceinline__ unsigned short f2bf(float f) {
    union { float f; unsigned u; } x; x.f = f;
    unsigned r = (x.u + 0x7FFFu + ((x.u >> 16) & 1u)) >> 16;
    return (unsigned short)r;
}

// HW packed convert: 2 fp32 -> 2 bf16 (RNE), one VALU op
__device__ __forceinline__ unsigned cvt2bf(float lo, float hi) {
    unsigned r;
    asm("v_cvt_pk_bf16_f32 %0, %1, %2" : "=v"(r) : "v"(lo), "v"(hi));
    return r;
}

__device__ __forceinline__ s16x8 zero8() {
    s16x8 z;
#pragma unroll
    for (int j = 0; j < 8; ++j) z[j] = 0;
    return z;
}

// 8 floats from 16B-aligned pointer -> bf16 frag via cvt_pk (4 ops)
__device__ __forceinline__ s16x8 cvt8g(const float* p) {
    float4 a = *(const float4*)p;
    float4 b = *(const float4*)(p + 4);
    union { unsigned u[4]; s16x8 v; } r;
    r.u[0] = cvt2bf(a.x, a.y); r.u[1] = cvt2bf(a.z, a.w);
    r.u[2] = cvt2bf(b.x, b.y); r.u[3] = cvt2bf(b.z, b.w);
    return r.v;
}

// k_logits x-tile LDS addressing: [col=(tl*16+v)][c], rows of 64 shorts (128B),
// 16B chunks XOR-swizzled by col hash so both scatter-writes and b128 reads spread banks.
__device__ __forceinline__ int xaddr(int col, int c) {
    int chunk = ((c >> 3) ^ (col & 7) ^ ((col >> 3) & 7)) & 7;
    return col * 64 + chunk * 8 + (c & 7);
}
__device__ __forceinline__ int xaddr16(int col, int ck) {  // ck = logical c chunk (c>>3)
    int chunk = (ck ^ (col & 7) ^ ((col >> 3) & 7)) & 7;
    return col * 64 + chunk * 8;
}

// ---------------------------------------------------------------------------
// K0: epilogue coefficients + Wd -> bf16 (once)
// ---------------------------------------------------------------------------
__global__ void k_prep(const float* __restrict__ bd, const float* __restrict__ gamma,
                       const float* __restrict__ beta, const float* __restrict__ Wd,
                       float* __restrict__ cmul, float* __restrict__ cadd,
                       unsigned short* __restrict__ wd_bf) {
    const int tid = threadIdx.x;
    if (blockIdx.x == 0 && tid < CC) {
        float mul = gamma[tid] * rsqrtf(1.0f + 1e-5f);
        float add = (bd[tid] + bd[CC + tid] + bd[2 * CC + tid]) * mul + beta[tid];
        cmul[tid] = mul;
        cadd[tid] = add;
    }
    for (int e = blockIdx.x * 256 + tid; e < SS * CC * CC; e += 16 * 256)
        wd_bf[e] = f2bf(Wd[e]);
}

// ---------------------------------------------------------------------------
// K1: logits partials. (unchanged from round-5/6/7 passing version)
// ---------------------------------------------------------------------------
__global__ __launch_bounds__(256) void k_logits(
    const float* __restrict__ x,
    const float* __restrict__ Wa, const float* __restrict__ ba,
    const float* __restrict__ Wb, const float* __restrict__ bb,
    float* __restrict__ part)   // [SLICES][N][S][256]
{
    const int b    = blockIdx.x;
    const int n    = b / SLICES;
    const int sl   = b % SLICES;
    const int tid  = threadIdx.x;
    const int lane = tid & 63;
    const int wave = tid >> 6;
    const int q    = lane >> 4;
    const int m    = lane & 15;

    __shared__ __align__(16) unsigned short xsb[128 * 64];     // 16KB swizzled x tile
    __shared__ __align__(16) unsigned short fa_l[SS][16][136]; // [s][v][k]
    __shared__ __align__(16) unsigned short fb_l[SS][16][136];

    // Wa/Wb A-frags + biases in registers
    s16x8 wa[SS][2], wb[SS][2];
    float4 ba_r[SS], bb_r[SS];
#pragma unroll
    for (int s = 0; s < SS; ++s) {
#pragma unroll
        for (int kt = 0; kt < 2; ++kt) {
            wa[s][kt] = cvt8g(Wa + ((size_t)(s * ICC + m) * CC + kt * 32 + q * 8));
            wb[s][kt] = cvt8g(Wb + ((size_t)(s * ICC + m) * CC + kt * 32 + q * 8));
        }
        ba_r[s] = *(const float4*)(ba + s * ICC + q * 4);
        bb_r[s] = *(const float4*)(bb + s * ICC + q * 4);
    }

    f32x4 accL[SS];
#pragma unroll
    for (int s = 0; s < SS; ++s)
#pragma unroll
        for (int r = 0; r < 4; ++r) accL[s][r] = 0.0f;

    const float* xn = x + (size_t)n * CC * TT * VV;
    const int tbase = sl * TSL;

    // prefetch chunk 0 into registers (coalesced: 2 rows x 512B per wave instr)
    float4 px[8];
#pragma unroll
    for (int i = 0; i < 8; ++i) {
        int f4 = tid + i * 256;
        int c = f4 >> 5, col4 = (f4 & 31) * 4;
        px[i] = *(const float4*)(xn + (size_t)c * (TT * VV) + (size_t)tbase * VV + col4);
    }

#pragma unroll
    for (int ch = 0; ch < CHUNKS; ++ch) {
        __syncthreads();                       // prev chunk's xsb reads complete
        // write staged regs -> swizzled LDS
#pragma unroll
        for (int i = 0; i < 8; ++i) {
            int f4 = tid + i * 256;
            int c = f4 >> 5, col4 = (f4 & 31) * 4;
            unsigned s01 = cvt2bf(px[i].x, px[i].y);
            unsigned s23 = cvt2bf(px[i].z, px[i].w);
            xsb[xaddr(col4 + 0, c)] = (unsigned short)(s01 & 0xffff);
            xsb[xaddr(col4 + 1, c)] = (unsigned short)(s01 >> 16);
            xsb[xaddr(col4 + 2, c)] = (unsigned short)(s23 & 0xffff);
            xsb[xaddr(col4 + 3, c)] = (unsigned short)(s23 >> 16);
        }
        __syncthreads();

        // B-frags: B[k=c][col=v], direct b128, no conversion
        s16x8 bx[2][2];
#pragma unroll
        for (int tli = 0; tli < 2; ++tli) {
            int col = (wave * 2 + tli) * 16 + m;
#pragma unroll
            for (int kt = 0; kt < 2; ++kt)
                bx[tli][kt] = *(const s16x8*)&xsb[xaddr16(col, kt * 4 + q)];
        }

        // prefetch next chunk (overlaps with MFMA phase below)
        if (ch + 1 < CHUNKS) {
#pragma unroll
            for (int i = 0; i < 8; ++i) {
                int f4 = tid + i * 256;
                int c = f4 >> 5, col4 = (f4 & 31) * 4;
                px[i] = *(const float4*)(xn + (size_t)c * (TT * VV) +
                                         (size_t)(tbase + (ch + 1) * 8) * VV + col4);
            }
        }

#pragma unroll
        for (int s = 0; s < SS; ++s) {
#pragma unroll
            for (int tli = 0; tli < 2; ++tli) {
                const int tl = wave * 2 + tli;
                f32x4 aa, ab;
                aa[0] = ba_r[s].x; aa[1] = ba_r[s].y; aa[2] = ba_r[s].z; aa[3] = ba_r[s].w;
                ab[0] = bb_r[s].x; ab[1] = bb_r[s].y; ab[2] = bb_r[s].z; ab[3] = bb_r[s].w;
#pragma unroll
                for (int kt = 0; kt < 2; ++kt) {
                    aa = MFMA16(wa[s][kt], bx[tli][kt], aa);
                    ab = MFMA16(wb[s][kt], bx[tli][kt], ab);
                }
                uint2 ua, ub;
                ua.x = cvt2bf(aa[0], aa[1]); ua.y = cvt2bf(aa[2], aa[3]);
                ub.x = cvt2bf(ab[0], ab[1]); ub.y = cvt2bf(ab[2], ab[3]);
                *reinterpret_cast<uint2*>(&fa_l[s][m][tl * 16 + 4 * q]) = ua;
                *reinterpret_cast<uint2*>(&fb_l[s][m][tl * 16 + 4 * q]) = ub;
            }
            // wave-private k-slice (exactly the t's this wave wrote)
            s16x8 A2 = *(const s16x8*)&fa_l[s][m][wave * 32 + q * 8];
            s16x8 B2 = *(const s16x8*)&fb_l[s][m][wave * 32 + q * 8];
            accL[s] = MFMA16(A2, B2, accL[s]);
        }
    }

    // cross-wave reduction (red overlays xsb: 12KB <= 16KB, xsb dead)
    __syncthreads();
    float* red = (float*)xsb;
#pragma unroll
    for (int s = 0; s < SS; ++s)
#pragma unroll
        for (int r = 0; r < 4; ++r)
            red[(s * 4 + wave) * 256 + (4 * q + r) * 16 + m] = accL[s][r];
    __syncthreads();
#pragma unroll
    for (int s = 0; s < SS; ++s) {
        float v = red[(s * 4 + 0) * 256 + tid] + red[(s * 4 + 1) * 256 + tid] +
                  red[(s * 4 + 2) * 256 + tid] + red[(s * 4 + 3) * 256 + tid];
        part[((size_t)(sl * NN + n) * SS + s) * 256 + tid] = v;
    }
}

// ---------------------------------------------------------------------------
// K2: sum slice partials, scale, softmax over v, add A_base+PA
// ---------------------------------------------------------------------------
__global__ __launch_bounds__(256) void k_softmax(
    const float* __restrict__ part,
    const float* __restrict__ A_base, const float* __restrict__ PA,
    float* __restrict__ att)
{
    const int n = blockIdx.x / SS;
    const int s = blockIdx.x % SS;
    const int tid = threadIdx.x;       // = v*16 + w
    const int w = tid & 15;

    __shared__ float l[256];
    size_t base = ((size_t)n * SS + s) * 256;
    float mine = 0.0f;
#pragma unroll
    for (int p = 0; p < SLICES; ++p)
        mine += part[(size_t)p * (NN * SS * 256) + base + tid];
    mine *= (1.0f / (ICC * TT));
    l[tid] = mine;
    __syncthreads();

    float mx = -1e30f;
#pragma unroll
    for (int v2 = 0; v2 < 16; ++v2) mx = fmaxf(mx, l[v2 * 16 + w]);
    float sm = 0.f;
#pragma unroll
    for (int v2 = 0; v2 < 16; ++v2) sm += __expf(l[v2 * 16 + w] - mx);
    float r = __expf(mine - mx) / sm;

    int aidx = (s * VV * VV) + tid;
    att[base + tid] = r + A_base[aidx] + PA[aidx];
}

// ---------------------------------------------------------------------------
// K3: out = (sum_s Wd_s @ (x (.) att_s)) * cmul + cadd + x.
// Round-8: r7 body + two 8-t sub-tiles per block with register-pipelined
// staging (k_logits pattern): sub-tile B's 8 float4 global loads issue right
// after A's xf extraction, hiding their latency under A's compute+epilogue.
//  - xsb (16KB swizzled bf16) reused per half; residual read back as bf16.
//  - zsb/osb union (18.4KB) per half; osb transpose -> 1KB/wave float4 stores.
//  - Wd frags hoisted to regs at top of each s-iteration (L2 latency hidden
//    under the Z round-trip).
// LDS 36.8KB -> 4 blocks/CU; grid 2304.
// ---------------------------------------------------------------------------
__global__ __launch_bounds__(256) void k_out(
    const float* __restrict__ x, const float* __restrict__ att,
    const unsigned short* __restrict__ wd_bf,
    const float* __restrict__ cmul, const float* __restrict__ cadd,
    float* __restrict__ out)
{
    const int b  = blockIdx.x;
    const int n  = b / (TT / OTB);
    const int t0 = (b % (TT / OTB)) * OTB;

    const int tid  = threadIdx.x;
    const int lane = tid & 63;
    const int wave = tid >> 6;
    const int q    = lane >> 4;
    const int m    = lane & 15;

    __shared__ __align__(16) unsigned short xsb[64 * 128];   // 16KB, per-half x tile
    __shared__ __align__(16) unsigned char zuni[18432];      // zsb then osb per half
    __shared__ __align__(16) unsigned short attL[SS][16][24];

    unsigned short* zsb = (unsigned short*)zuni;  // [wave][32][72] bf16
    float*          osb = (float*)zuni;           // [32][140] fp32 (17.9KB)

    const float* xn = x + (size_t)(n * CC) * TT * VV;

    // ---- prefetch sub-tile A's x rows into registers ----
    float4 px[8];
#pragma unroll
    for (int i = 0; i < 8; ++i) {
        int f4   = tid + i * 256;
        int c    = f4 >> 5;                  // 0..63
        int col4 = (f4 & 31) * 4;            // tcol, 0..124
        px[i] = *(const float4*)(xn + (size_t)c * (TT * VV) + (size_t)t0 * VV + col4);
    }
    // ---- stage att (once per block) ----
    for (int e = tid; e < SS * 256; e += 256) {
        int ss = e >> 8, vv = (e >> 4) & 15, ww = e & 15;
        attL[ss][ww][vv] = f2bf(att[((size_t)n * SS + ss) * 256 + vv * 16 + ww]);
    }

    for (int half = 0; half < 2; ++half) {
        const int th = t0 + half * 8;

        // ---- write staged regs -> swizzled xsb ----
#pragma unroll
        for (int i = 0; i < 8; ++i) {
            int f4   = tid + i * 256;
            int c    = f4 >> 5;
            int col4 = (f4 & 31) * 4;
            uint2 u2; u2.x = cvt2bf(px[i].x, px[i].y); u2.y = cvt2bf(px[i].z, px[i].w);
            int chunk = (col4 >> 3) ^ (c & 7);
            *(uint2*)&xsb[c * 128 + chunk * 8 + (col4 & 7)] = u2;
        }
        __syncthreads();

        // ---- x A-frags: A[c_local=m][k=v], q>=2 zero (K 16->32 pad) ----
        s16x8 xf[4][2];
#pragma unroll
        for (int cc = 0; cc < 4; ++cc)
#pragma unroll
            for (int u = 0; u < 2; ++u) {
                s16x8 f = zero8();
                if (q < 2) {
                    int c = cc * 16 + m;
                    int t = wave * 2 + u;
                    int chunk = (2 * t + q) ^ (c & 7);
                    f = *(const s16x8*)&xsb[c * 128 + chunk * 8];
                }
                xf[cc][u] = f;
            }

        // ---- prefetch sub-tile B now: latency hides under A's compute ----
        if (half == 0) {
#pragma unroll
            for (int i = 0; i < 8; ++i) {
                int f4   = tid + i * 256;
                int c    = f4 >> 5;
                int col4 = (f4 & 31) * 4;
                px[i] = *(const float4*)(xn + (size_t)c * (TT * VV) +
                                         (size_t)(t0 + 8) * VV + col4);
            }
        }

        f32x4 acc[4][2];
#pragma unroll
        for (int p = 0; p < 4; ++p)
#pragma unroll
            for (int u = 0; u < 2; ++u)
#pragma unroll
                for (int r = 0; r < 4; ++r) acc[p][u][r] = 0.0f;

#pragma unroll
        for (int s = 0; s < SS; ++s) {
            // hoisted Wd loads: 8 independent b128 from L2-hot wd_bf
            s16x8 wf[4][2];
#pragma unroll
            for (int p = 0; p < 4; ++p)
#pragma unroll
                for (int kt = 0; kt < 2; ++kt)
                    wf[p][kt] = *(const s16x8*)(wd_bf +
                                  ((size_t)(s * CC + p * 16 + m) * CC + kt * 32 + q * 8));

            s16x8 af = zero8();
            if (q < 2) af = *(const s16x8*)&attL[s][m][q * 8];

            // Z = x . att -> zsb bf16 (wave-private; write-side cvt_pk)
#pragma unroll
            for (int u = 0; u < 2; ++u)
#pragma unroll
                for (int cc = 0; cc < 4; ++cc) {
                    f32x4 z;
#pragma unroll
                    for (int r = 0; r < 4; ++r) z[r] = 0.0f;
                    z = MFMA16(xf[cc][u], af, z);
                    uint2 uz; uz.x = cvt2bf(z[0], z[1]); uz.y = cvt2bf(z[2], z[3]);
                    *(uint2*)&zsb[(wave * 32 + u * 16 + m) * 72 + cc * 16 + 4 * q] = uz;
                }

            // Z B-frags: pure b128 reads (same-wave RAW, lgkmcnt-ordered)
            s16x8 zf[2][2];
#pragma unroll
            for (int u = 0; u < 2; ++u)
#pragma unroll
                for (int kt = 0; kt < 2; ++kt)
                    zf[u][kt] = *(const s16x8*)&zsb[(wave * 32 + u * 16 + m) * 72 +
                                                    kt * 32 + q * 8];

            // Y += Wd_s @ Z
#pragma unroll
            for (int p = 0; p < 4; ++p)
#pragma unroll
                for (int u = 0; u < 2; ++u)
#pragma unroll
                    for (int kt = 0; kt < 2; ++kt)
                        acc[p][u] = MFMA16(wf[p][kt], zf[u][kt], acc[p][u]);
        }

        // ---- BN scale/shift into acc ----
#pragma unroll
        for (int p = 0; p < 4; ++p) {
            float4 mu = *(const float4*)(cmul + p * 16 + 4 * q);
            float4 ad = *(const float4*)(cadd + p * 16 + 4 * q);
            float mur[4] = {mu.x, mu.y, mu.z, mu.w};
            float adr[4] = {ad.x, ad.y, ad.z, ad.w};
#pragma unroll
            for (int u = 0; u < 2; ++u)
#pragma unroll
                for (int r = 0; r < 4; ++r)
                    acc[p][u][r] = acc[p][u][r] * mur[r] + adr[r];
        }

        // ---- osb transpose, two 32-row halves; residual (bf16) from xsb ----
        const size_t obase = ((size_t)(n * CC) * TT + th) * VV;
#pragma unroll
        for (int hp = 0; hp < 2; ++hp) {
            __syncthreads();   // zsb reads (hp=0) / prev osb reads (hp=1) done
#pragma unroll
            for (int pp = 0; pp < 2; ++pp)
#pragma unroll
                for (int u = 0; u < 2; ++u)
#pragma unroll
                    for (int r = 0; r < 4; ++r)
                        osb[(pp * 16 + 4 * q + r) * 140 + (wave * 2 + u) * 16 + m] =
                            acc[hp * 2 + pp][u][r];
            __syncthreads();
#pragma unroll
            for (int k = 0; k < 4; ++k) {
                int idx  = tid + k * 256;
                int row  = idx >> 5;             // 0..31
                int col4 = (idx & 31) * 4;       // 0..124
                int o    = hp * 32 + row;
                float4 v = *(const float4*)&osb[row * 140 + col4];
                int chunk = (col4 >> 3) ^ (o & 7);
                uint2 xb = *(const uint2*)&xsb[o * 128 + chunk * 8 + (col4 & 7)];
                union { unsigned u32; float f; } c0, c1, c2, c3;
                c0.u32 = xb.x << 16;  c1.u32 = xb.x & 0xffff0000u;
                c2.u32 = xb.y << 16;  c3.u32 = xb.y & 0xffff0000u;
                float4 res;
                res.x = v.x + c0.f; res.y = v.y + c1.f;
                res.z = v.z + c2.f; res.w = v.w + c3.f;
                *(float4*)(out + obase + (size_t)o * (TT * VV) + col4) = res;
            }
        }
        __syncthreads();   // xsb residual reads done -> safe to overwrite for B
    }
}

// ---------------------------------------------------------------------------
extern "C" void kernel_launch(void* const* d_in, const int* in_sizes, int n_in,
                              void* d_out, int out_size, void* d_ws, size_t ws_size,
                              hipStream_t stream) {
    const float* x      = (const float*)d_in[0];
    const float* A_base = (const float*)d_in[1];
    const float* PA     = (const float*)d_in[2];
    const float* Wa     = (const float*)d_in[3];
    const float* ba     = (const float*)d_in[4];
    const float* Wb     = (const float*)d_in[5];
    const float* bb     = (const float*)d_in[6];
    const float* Wd     = (const float*)d_in[7];
    const float* bd     = (const float*)d_in[8];
    const float* gamma  = (const float*)d_in[9];
    const float* beta   = (const float*)d_in[10];
    float* out = (float*)d_out;

    float* part = (float*)d_ws;                        // [SLICES][N][S][256]
    float* att  = part;                                // overlays slice 0 (safe)
    float* cmul = part + (size_t)SLICES * NN * SS * 256;
    float* cadd = cmul + CC;
    unsigned short* wd_bf = (unsigned short*)(cadd + CC);  // 16B-aligned

    k_prep<<<16, 256, 0, stream>>>(bd, gamma, beta, Wd, cmul, cadd, wd_bf);
    k_logits<<<NN * SLICES, 256, 0, stream>>>(x, Wa, ba, Wb, bb, part);
    k_softmax<<<NN * SS, 256, 0, stream>>>(part, A_base, PA, att);
    k_out<<<NN * (TT / OTB), 256, 0, stream>>>(x, att, wd_bf, cmul, cadd, out);
}

// Round 9
// 340.245 us; speedup vs baseline: 1.0717x; 1.0717x over previous
//
#include <hip/hip_runtime.h>
#include <math.h>

#define NN 128
#define CC 64
#define TT 288
#define VV 16
#define SS 3
#define ICC 16

#define SLICES 12
#define TSL (TT / SLICES)      // 24 t's per slice
#define CHUNKS (TSL / 8)       // 3 chunks of 8 t's

#define OTB 16                 // k_out t-tile

typedef __attribute__((ext_vector_type(8))) short s16x8;
typedef __attribute__((ext_vector_type(4))) float f32x4;

#define MFMA16(a, b, c) __builtin_amdgcn_mfma_f32_16x16x32_bf16(a, b, c, 0, 0, 0)

__device__ __forceinline__ unsigned short f2bf(float f) {
    union { float f; unsigned u; } x; x.f = f;
    unsigned r = (x.u + 0x7FFFu + ((x.u >> 16) & 1u)) >> 16;
    return (unsigned short)r;
}

// HW packed convert: 2 fp32 -> 2 bf16 (RNE), one VALU op
__device__ __forceinline__ unsigned cvt2bf(float lo, float hi) {
    unsigned r;
    asm("v_cvt_pk_bf16_f32 %0, %1, %2" : "=v"(r) : "v"(lo), "v"(hi));
    return r;
}

__device__ __forceinline__ s16x8 zero8() {
    s16x8 z;
#pragma unroll
    for (int j = 0; j < 8; ++j) z[j] = 0;
    return z;
}

// 8 floats from 16B-aligned pointer -> bf16 frag via cvt_pk (4 ops)
__device__ __forceinline__ s16x8 cvt8g(const float* p) {
    float4 a = *(const float4*)p;
    float4 b = *(const float4*)(p + 4);
    union { unsigned u[4]; s16x8 v; } r;
    r.u[0] = cvt2bf(a.x, a.y); r.u[1] = cvt2bf(a.z, a.w);
    r.u[2] = cvt2bf(b.x, b.y); r.u[3] = cvt2bf(b.z, b.w);
    return r.v;
}

// k_logits x-tile LDS addressing: [col=(tl*16+v)][c], rows of 64 shorts (128B),
// 16B chunks XOR-swizzled by col hash so both scatter-writes and b128 reads spread banks.
__device__ __forceinline__ int xaddr(int col, int c) {
    int chunk = ((c >> 3) ^ (col & 7) ^ ((col >> 3) & 7)) & 7;
    return col * 64 + chunk * 8 + (c & 7);
}
__device__ __forceinline__ int xaddr16(int col, int ck) {  // ck = logical c chunk (c>>3)
    int chunk = (ck ^ (col & 7) ^ ((col >> 3) & 7)) & 7;
    return col * 64 + chunk * 8;
}

// ---------------------------------------------------------------------------
// K0: epilogue coefficients + Wd -> bf16 (once)
// ---------------------------------------------------------------------------
__global__ void k_prep(const float* __restrict__ bd, const float* __restrict__ gamma,
                       const float* __restrict__ beta, const float* __restrict__ Wd,
                       float* __restrict__ cmul, float* __restrict__ cadd,
                       unsigned short* __restrict__ wd_bf) {
    const int tid = threadIdx.x;
    if (blockIdx.x == 0 && tid < CC) {
        float mul = gamma[tid] * rsqrtf(1.0f + 1e-5f);
        float add = (bd[tid] + bd[CC + tid] + bd[2 * CC + tid]) * mul + beta[tid];
        cmul[tid] = mul;
        cadd[tid] = add;
    }
    for (int e = blockIdx.x * 256 + tid; e < SS * CC * CC; e += 16 * 256)
        wd_bf[e] = f2bf(Wd[e]);
}

// ---------------------------------------------------------------------------
// K1: logits partials. Block = (n, t-slice of 24). All 3 subsets share x.
// ONE delta vs round-2: fa_l/fb_l are single-s bands [16][136] reused across
// the s-loop (same-wave in-order LDS RAW — the identical reuse pattern already
// exercised across chunks in r1/r2/r5). LDS 41.5KB -> 24.5KB => 3 -> 6
// blocks/CU for latency hiding.
// ---------------------------------------------------------------------------
__global__ __launch_bounds__(256) void k_logits(
    const float* __restrict__ x,
    const float* __restrict__ Wa, const float* __restrict__ ba,
    const float* __restrict__ Wb, const float* __restrict__ bb,
    float* __restrict__ part)   // [SLICES][N][S][256]
{
    const int b    = blockIdx.x;
    const int n    = b / SLICES;
    const int sl   = b % SLICES;
    const int tid  = threadIdx.x;
    const int lane = tid & 63;
    const int wave = tid >> 6;
    const int q    = lane >> 4;
    const int m    = lane & 15;

    __shared__ __align__(16) unsigned short xsb[128 * 64];   // 16KB swizzled x tile
    __shared__ __align__(16) unsigned short fa_l[16][136];   // [v][k] wave bands
    __shared__ __align__(16) unsigned short fb_l[16][136];

    // Wa/Wb A-frags + biases in registers
    s16x8 wa[SS][2], wb[SS][2];
    float4 ba_r[SS], bb_r[SS];
#pragma unroll
    for (int s = 0; s < SS; ++s) {
#pragma unroll
        for (int kt = 0; kt < 2; ++kt) {
            wa[s][kt] = cvt8g(Wa + ((size_t)(s * ICC + m) * CC + kt * 32 + q * 8));
            wb[s][kt] = cvt8g(Wb + ((size_t)(s * ICC + m) * CC + kt * 32 + q * 8));
        }
        ba_r[s] = *(const float4*)(ba + s * ICC + q * 4);
        bb_r[s] = *(const float4*)(bb + s * ICC + q * 4);
    }

    f32x4 accL[SS];
#pragma unroll
    for (int s = 0; s < SS; ++s)
#pragma unroll
        for (int r = 0; r < 4; ++r) accL[s][r] = 0.0f;

    const float* xn = x + (size_t)n * CC * TT * VV;
    const int tbase = sl * TSL;

    // prefetch chunk 0 into registers (coalesced: 2 rows x 512B per wave instr)
    float4 px[8];
#pragma unroll
    for (int i = 0; i < 8; ++i) {
        int f4 = tid + i * 256;
        int c = f4 >> 5, col4 = (f4 & 31) * 4;
        px[i] = *(const float4*)(xn + (size_t)c * (TT * VV) + (size_t)tbase * VV + col4);
    }

#pragma unroll
    for (int ch = 0; ch < CHUNKS; ++ch) {
        __syncthreads();                       // prev chunk's xsb reads complete
        // write staged regs -> swizzled LDS
#pragma unroll
        for (int i = 0; i < 8; ++i) {
            int f4 = tid + i * 256;
            int c = f4 >> 5, col4 = (f4 & 31) * 4;
            unsigned s01 = cvt2bf(px[i].x, px[i].y);
            unsigned s23 = cvt2bf(px[i].z, px[i].w);
            xsb[xaddr(col4 + 0, c)] = (unsigned short)(s01 & 0xffff);
            xsb[xaddr(col4 + 1, c)] = (unsigned short)(s01 >> 16);
            xsb[xaddr(col4 + 2, c)] = (unsigned short)(s23 & 0xffff);
            xsb[xaddr(col4 + 3, c)] = (unsigned short)(s23 >> 16);
        }
        __syncthreads();

        // B-frags: B[k=c][col=v], direct b128, no conversion
        s16x8 bx[2][2];
#pragma unroll
        for (int tli = 0; tli < 2; ++tli) {
            int col = (wave * 2 + tli) * 16 + m;
#pragma unroll
            for (int kt = 0; kt < 2; ++kt)
                bx[tli][kt] = *(const s16x8*)&xsb[xaddr16(col, kt * 4 + q)];
        }

        // prefetch next chunk (overlaps with MFMA phase below)
        if (ch + 1 < CHUNKS) {
#pragma unroll
            for (int i = 0; i < 8; ++i) {
                int f4 = tid + i * 256;
                int c = f4 >> 5, col4 = (f4 & 31) * 4;
                px[i] = *(const float4*)(xn + (size_t)c * (TT * VV) +
                                         (size_t)(tbase + (ch + 1) * 8) * VV + col4);
            }
        }

#pragma unroll
        for (int s = 0; s < SS; ++s) {
#pragma unroll
            for (int tli = 0; tli < 2; ++tli) {
                const int tl = wave * 2 + tli;
                f32x4 aa, ab;
                aa[0] = ba_r[s].x; aa[1] = ba_r[s].y; aa[2] = ba_r[s].z; aa[3] = ba_r[s].w;
                ab[0] = bb_r[s].x; ab[1] = bb_r[s].y; ab[2] = bb_r[s].z; ab[3] = bb_r[s].w;
#pragma unroll
                for (int kt = 0; kt < 2; ++kt) {
                    aa = MFMA16(wa[s][kt], bx[tli][kt], aa);
                    ab = MFMA16(wb[s][kt], bx[tli][kt], ab);
                }
                // D[i=4q+r][v=m] -> fa_l[v][k=tl*16+i]; wave-private col band
                uint2 ua, ub;
                ua.x = cvt2bf(aa[0], aa[1]); ua.y = cvt2bf(aa[2], aa[3]);
                ub.x = cvt2bf(ab[0], ab[1]); ub.y = cvt2bf(ab[2], ab[3]);
                *reinterpret_cast<uint2*>(&fa_l[m][tl * 16 + 4 * q]) = ua;
                *reinterpret_cast<uint2*>(&fb_l[m][tl * 16 + 4 * q]) = ub;
            }
            // same-wave RAW on the band: LDS ops from one wave execute in order
            s16x8 A2 = *(const s16x8*)&fa_l[m][wave * 32 + q * 8];
            s16x8 B2 = *(const s16x8*)&fb_l[m][wave * 32 + q * 8];
            accL[s] = MFMA16(A2, B2, accL[s]);
        }
    }

    // cross-wave reduction (red overlays xsb: 12KB <= 16KB, xsb dead)
    __syncthreads();
    float* red = (float*)xsb;
#pragma unroll
    for (int s = 0; s < SS; ++s)
#pragma unroll
        for (int r = 0; r < 4; ++r)
            red[(s * 4 + wave) * 256 + (4 * q + r) * 16 + m] = accL[s][r];
    __syncthreads();
#pragma unroll
    for (int s = 0; s < SS; ++s) {
        float v = red[(s * 4 + 0) * 256 + tid] + red[(s * 4 + 1) * 256 + tid] +
                  red[(s * 4 + 2) * 256 + tid] + red[(s * 4 + 3) * 256 + tid];
        part[((size_t)(sl * NN + n) * SS + s) * 256 + tid] = v;
    }
}

// ---------------------------------------------------------------------------
// K2: sum slice partials, scale, softmax over v, add A_base+PA
// ---------------------------------------------------------------------------
__global__ __launch_bounds__(256) void k_softmax(
    const float* __restrict__ part,
    const float* __restrict__ A_base, const float* __restrict__ PA,
    float* __restrict__ att)
{
    const int n = blockIdx.x / SS;
    const int s = blockIdx.x % SS;
    const int tid = threadIdx.x;       // = v*16 + w
    const int w = tid & 15;

    __shared__ float l[256];
    size_t base = ((size_t)n * SS + s) * 256;
    float mine = 0.0f;
#pragma unroll
    for (int p = 0; p < SLICES; ++p)
        mine += part[(size_t)p * (NN * SS * 256) + base + tid];
    mine *= (1.0f / (ICC * TT));
    l[tid] = mine;
    __syncthreads();

    float mx = -1e30f;
#pragma unroll
    for (int v2 = 0; v2 < 16; ++v2) mx = fmaxf(mx, l[v2 * 16 + w]);
    float sm = 0.f;
#pragma unroll
    for (int v2 = 0; v2 < 16; ++v2) sm += __expf(l[v2 * 16 + w] - mx);
    float r = __expf(mine - mx) / sm;

    int aidx = (s * VV * VV) + tid;
    att[base + tid] = r + A_base[aidx] + PA[aidx];
}

// ---------------------------------------------------------------------------
// K3: out = (sum_s Wd_s @ (x (.) att_s)) * cmul + cadd + x.
// Round-2 version VERBATIM (best measured: hidden under the 90us fills).
// 16-t tile. x staged via 1KB coalesced row reads into swizzled bf16 LDS;
// Wd staged in LDS; output through fp32 osb in two 32-row passes ->
// contiguous 1KB stores with fp32 residual folded in.
// ---------------------------------------------------------------------------
__global__ __launch_bounds__(256) void k_out(
    const float* __restrict__ x, const float* __restrict__ att,
    const unsigned short* __restrict__ wd_bf,
    const float* __restrict__ cmul, const float* __restrict__ cadd,
    float* __restrict__ out)
{
    const int b  = blockIdx.x;
    const int n  = b / (TT / OTB);
    const int t0 = (b % (TT / OTB)) * OTB;

    const int tid  = threadIdx.x;
    const int lane = tid & 63;
    const int wave = tid >> 6;
    const int q    = lane >> 4;
    const int m    = lane & 15;

    __shared__ __align__(16) unsigned char uni[36864];
    __shared__ __align__(16) unsigned short wdl[SS * 64 * 64];  // 24KB swizzled Wd
    __shared__ __align__(16) unsigned short attL[SS][16][24];

    unsigned short* xsb = (unsigned short*)uni;  // [c][256] swizzled 16B chunks
    unsigned short* zsb = (unsigned short*)uni;  // [wave][64][72]
    float*          osb = (float*)uni;           // [32][268]

    // ---- stage x tile: wave reads 16 full 1KB rows, writes swizzled bf16 ----
    {
        const float* xrow0 = x + ((size_t)(n * CC) * TT + t0) * VV;
#pragma unroll
        for (int i = 0; i < 16; ++i) {
            int c = wave * 16 + i;
            float4 f = *(const float4*)(xrow0 + (size_t)c * (TT * VV) + lane * 4);
            uint2 u2; u2.x = cvt2bf(f.x, f.y); u2.y = cvt2bf(f.z, f.w);
            int tcol  = lane * 4;
            int chunk = (tcol >> 3) ^ (c & 7);
            *(uint2*)&xsb[c * 256 + chunk * 8 + (tcol & 7)] = u2;
        }
    }
    // ---- stage Wd (bf16, swizzled 16B chunks per 64-short row) ----
#pragma unroll
    for (int i = 0; i < 12; ++i) {
        int g  = tid + i * 256;          // uint2 index, 3072 total
        int s  = g >> 10;
        int r1 = g & 1023;
        int o  = r1 >> 4, c4 = r1 & 15;
        uint2 w2 = *(const uint2*)(wd_bf + ((size_t)(s * 64 + o) * 64 + c4 * 4));
        int chunk = (c4 >> 1) ^ (o & 7);
        *(uint2*)&wdl[(s * 64 + o) * 64 + chunk * 8 + (c4 & 1) * 4] = w2;
    }
    // ---- stage att ----
    for (int e = tid; e < SS * 256; e += 256) {
        int ss = e >> 8, vv = (e >> 4) & 15, ww = e & 15;
        attL[ss][ww][vv] = f2bf(att[((size_t)n * SS + ss) * 256 + vv * 16 + ww]);
    }

    __syncthreads();

    // ---- x A-frags from LDS: A[c_local=m][k=v], q>=2 zero (K 16->32 pad) ----
    s16x8 xf[4][4];   // [cc][u]
#pragma unroll
    for (int cc = 0; cc < 4; ++cc)
#pragma unroll
        for (int u = 0; u < 4; ++u) {
            s16x8 f = zero8();
            if (q < 2) {
                int c = cc * 16 + m;
                int chunk = ((4 * wave + u) * 2 + q) ^ (c & 7);
                f = *(const s16x8*)&xsb[c * 256 + chunk * 8];
            }
            xf[cc][u] = f;
        }

    __syncthreads();   // xsb dead -> zsb region live

    f32x4 acc[4][4];
#pragma unroll
    for (int p = 0; p < 4; ++p)
#pragma unroll
        for (int u = 0; u < 4; ++u)
#pragma unroll
            for (int r = 0; r < 4; ++r) acc[p][u][r] = 0.0f;

#pragma unroll
    for (int s = 0; s < SS; ++s) {
        s16x8 af = zero8();
        if (q < 2) af = *(const s16x8*)&attL[s][m][q * 8];

        // Z = x . att -> zsb bf16 (write-side cvt_pk, b64 writes)
#pragma unroll
        for (int u = 0; u < 4; ++u)
#pragma unroll
            for (int cc = 0; cc < 4; ++cc) {
                f32x4 z;
#pragma unroll
                for (int r = 0; r < 4; ++r) z[r] = 0.0f;
                z = MFMA16(xf[cc][u], af, z);
                uint2 uz; uz.x = cvt2bf(z[0], z[1]); uz.y = cvt2bf(z[2], z[3]);
                *(uint2*)&zsb[((wave * 64) + u * 16 + m) * 72 + cc * 16 + 4 * q] = uz;
            }

        // B-frags of Z: pure b128 reads
        s16x8 zf[4][2];
#pragma unroll
        for (int u = 0; u < 4; ++u)
#pragma unroll
            for (int kt = 0; kt < 2; ++kt)
                zf[u][kt] = *(const s16x8*)&zsb[((wave * 64) + u * 16 + m) * 72 +
                                                kt * 32 + q * 8];

        // Y += Wd_s @ Z
#pragma unroll
        for (int p = 0; p < 4; ++p) {
            s16x8 wf[2];
#pragma unroll
            for (int kt = 0; kt < 2; ++kt) {
                int o = p * 16 + m;
                int chunk = (kt * 4 + q) ^ (o & 7);
                wf[kt] = *(const s16x8*)&wdl[(s * 64 + o) * 64 + chunk * 8];
            }
#pragma unroll
            for (int u = 0; u < 4; ++u)
#pragma unroll
                for (int kt = 0; kt < 2; ++kt)
                    acc[p][u] = MFMA16(wf[kt], zf[u][kt], acc[p][u]);
        }
    }

    // ---- BN scale/shift into acc ----
#pragma unroll
    for (int p = 0; p < 4; ++p) {
        float4 mu = *(const float4*)(cmul + p * 16 + 4 * q);
        float4 ad = *(const float4*)(cadd + p * 16 + 4 * q);
        float mur[4] = {mu.x, mu.y, mu.z, mu.w};
        float adr[4] = {ad.x, ad.y, ad.z, ad.w};
#pragma unroll
        for (int u = 0; u < 4; ++u)
#pragma unroll
            for (int r = 0; r < 4; ++r)
                acc[p][u][r] = acc[p][u][r] * mur[r] + adr[r];
    }

    // ---- coalesced store via osb, two 32-row halves; residual folded in ----
#pragma unroll
    for (int hp = 0; hp < 2; ++hp) {
        __syncthreads();   // zsb (hp=0) / previous osb reads (hp=1) complete
#pragma unroll
        for (int pp = 0; pp < 2; ++pp)
#pragma unroll
            for (int u = 0; u < 4; ++u)
#pragma unroll
                for (int r = 0; r < 4; ++r)
                    osb[(pp * 16 + 4 * q + r) * 268 + (4 * wave + u) * 16 + m] =
                        acc[hp * 2 + pp][u][r];
        __syncthreads();
#pragma unroll
        for (int j = 0; j < 8; ++j) {
            int orow = wave * 8 + j;
            int o = hp * 32 + orow;
            float4 v = *(const float4*)&osb[orow * 268 + lane * 4];
            size_t off = ((size_t)(n * CC + o) * TT + t0) * VV + lane * 4;
            float4 xr = *(const float4*)(x + off);
            float4 res;
            res.x = v.x + xr.x; res.y = v.y + xr.y;
            res.z = v.z + xr.z; res.w = v.w + xr.w;
            *(float4*)(out + off) = res;
        }
    }
}

// ---------------------------------------------------------------------------
extern "C" void kernel_launch(void* const* d_in, const int* in_sizes, int n_in,
                              void* d_out, int out_size, void* d_ws, size_t ws_size,
                              hipStream_t stream) {
    const float* x      = (const float*)d_in[0];
    const float* A_base = (const float*)d_in[1];
    const float* PA     = (const float*)d_in[2];
    const float* Wa     = (const float*)d_in[3];
    const float* ba     = (const float*)d_in[4];
    const float* Wb     = (const float*)d_in[5];
    const float* bb     = (const float*)d_in[6];
    const float* Wd     = (const float*)d_in[7];
    const float* bd     = (const float*)d_in[8];
    const float* gamma  = (const float*)d_in[9];
    const float* beta   = (const float*)d_in[10];
    float* out = (float*)d_out;

    float* part = (float*)d_ws;                        // [SLICES][N][S][256]
    float* att  = part;                                // overlays slice 0 (safe)
    float* cmul = part + (size_t)SLICES * NN * SS * 256;
    float* cadd = cmul + CC;
    unsigned short* wd_bf = (unsigned short*)(cadd + CC);  // 16B-aligned

    k_prep<<<16, 256, 0, stream>>>(bd, gamma, beta, Wd, cmul, cadd, wd_bf);
    k_logits<<<NN * SLICES, 256, 0, stream>>>(x, Wa, ba, Wb, bb, part);
    k_softmax<<<NN * SS, 256, 0, stream>>>(part, A_base, PA, att);
    k_out<<<NN * (TT / OTB), 256, 0, stream>>>(x, att, wd_bf, cmul, cadd, out);
}